// Round 9
// baseline (345.382 us; speedup 1.0000x reference)
//
#include <hip/hip_runtime.h>
#include <hip/hip_fp16.h>
#include <math.h>

#define N_NODES 50000
#define E_EDGES 800000
#define NEG_SLOPE 0.2f
#define BN_EPS 1e-5f

#define BK_SHIFT 9                       // 512-node buckets
#define NBK 98                           // ceil(50000/512)
#define L1_BLOCKS 256
#define L1_CHUNK (E_EDGES / L1_BLOCKS)   // 3125 exactly
#define CNT_N (NBK * L1_BLOCKS)          // 25088
#define SCG_BLOCKS ((CNT_N + 1023) / 1024)  // 25
#define STAGE_MAX 9216                   // per-bucket staging

typedef __attribute__((ext_vector_type(8))) _Float16 half8;
typedef __attribute__((ext_vector_type(4))) float f32x4;

__device__ __forceinline__ float lrelu(float v) { return v > 0.f ? v : NEG_SLOPE * v; }

// ---------------- init (BN accumulators only) ----------------
__global__ void k_zero(float* __restrict__ bn_sum, float* __restrict__ bn_sumsq) {
  int t = threadIdx.x;
  if (t < 128) { bn_sum[t] = 0.f; bn_sumsq[t] = 0.f; }
}

// ---------------- fp16 weight transpose-converts ----------------
__global__ void k_cvtW(const float* __restrict__ W0, const float* __restrict__ W1,
                       _Float16* __restrict__ W0t, _Float16* __restrict__ W1t) {
  int t = threadIdx.x;
  for (int idx = t; idx < 128 * 128; idx += 256) {
    int k = idx >> 7, c = idx & 127;
    W0t[c * 128 + k] = (_Float16)W0[idx];
  }
  for (int idx = t; idx < 128 * 64; idx += 256) {
    int k = idx >> 6, c = idx & 63;
    W1t[c * 128 + k] = (_Float16)W1[idx];
  }
}

// ---- L1: per-block bucket histogram ----
__global__ __launch_bounds__(256) void k_l1hist(const int* __restrict__ dst,
                                                int* __restrict__ cnt) {
  __shared__ int lcnt[NBK];
  int t = threadIdx.x;
  if (t < NBK) lcnt[t] = 0;
  __syncthreads();
  int beg = blockIdx.x * L1_CHUNK, end = beg + L1_CHUNK;
  for (int e = beg + t; e < end; e += 256)
    atomicAdd(&lcnt[((unsigned int)dst[e]) >> BK_SHIFT], 1);
  __syncthreads();
  for (int b = t; b < NBK; b += 256) cnt[b * L1_BLOCKS + blockIdx.x] = lcnt[b];
}

// ---- hierarchical exclusive scan over CNT_N ----
__global__ __launch_bounds__(256) void k_scan1g(const int* __restrict__ cnt,
                                                int* __restrict__ tmp,
                                                int* __restrict__ bsums) {
  __shared__ int ts[256];
  int t = threadIdx.x;
  int base = blockIdx.x * 1024 + t * 4;
  int c0 = (base + 0 < CNT_N) ? cnt[base + 0] : 0;
  int c1 = (base + 1 < CNT_N) ? cnt[base + 1] : 0;
  int c2 = (base + 2 < CNT_N) ? cnt[base + 2] : 0;
  int c3 = (base + 3 < CNT_N) ? cnt[base + 3] : 0;
  int s = c0 + c1 + c2 + c3;
  ts[t] = s;
  __syncthreads();
  for (int off = 1; off < 256; off <<= 1) {
    int v = (t >= off) ? ts[t - off] : 0;
    __syncthreads();
    ts[t] += v;
    __syncthreads();
  }
  int excl = ts[t] - s;
  if (t == 255) bsums[blockIdx.x] = ts[255];
  if (base + 0 < CNT_N) tmp[base + 0] = excl;
  if (base + 1 < CNT_N) tmp[base + 1] = excl + c0;
  if (base + 2 < CNT_N) tmp[base + 2] = excl + c0 + c1;
  if (base + 3 < CNT_N) tmp[base + 3] = excl + c0 + c1 + c2;
}

__global__ void k_scan2g(int* __restrict__ bsums) {
  int t = threadIdx.x;
  int orig = (t < SCG_BLOCKS) ? bsums[t] : 0;
  int v = orig;
#pragma unroll
  for (int off = 1; off < 64; off <<= 1) {
    int u = __shfl_up(v, off);
    if (t >= off) v += u;
  }
  if (t < SCG_BLOCKS) bsums[t] = v - orig;
}

// ---- L1 scatter: deterministic bases per (bucket,block) ----
__global__ __launch_bounds__(256) void k_l1scatter(const int* __restrict__ src,
                                                   const int* __restrict__ dst,
                                                   const int* __restrict__ tmp,
                                                   const int* __restrict__ bsums,
                                                   unsigned int* __restrict__ binned) {
  __shared__ int cur[NBK];
  int t = threadIdx.x;
  for (int b = t; b < NBK; b += 256) {
    int idx = b * L1_BLOCKS + blockIdx.x;
    cur[b] = tmp[idx] + bsums[idx >> 10];
  }
  __syncthreads();
  int beg = blockIdx.x * L1_CHUNK, end = beg + L1_CHUNK;
  for (int e = beg + t; e < end; e += 256) {
    unsigned int d = (unsigned int)dst[e];
    int b = d >> BK_SHIFT;
    int p = atomicAdd(&cur[b], 1);
    binned[p] = ((unsigned int)src[e] << 16) | d;
  }
}

__global__ void k_bbase(const int* __restrict__ tmp, const int* __restrict__ bsums,
                        int* __restrict__ bucket_base) {
  int b = threadIdx.x;
  if (b < NBK) {
    int idx = b * L1_BLOCKS;
    bucket_base[b] = tmp[idx] + bsums[idx >> 10];
  }
  if (b == NBK) bucket_base[NBK] = E_EDGES;
}

// ---- L2: per-bucket LDS counting sort ----
__global__ __launch_bounds__(256) void k_scatter3(const int* __restrict__ bucket_base,
                                                  const unsigned int* __restrict__ binned,
                                                  int* __restrict__ row_ptr,
                                                  int* __restrict__ csr_src) {
  __shared__ int cnt[512];
  __shared__ int staging[STAGE_MAX];
  __shared__ int ts[256];
  int t = threadIdx.x;
  int b = blockIdx.x;
  int lo = b << BK_SHIFT;
  int hi = lo + 512; if (hi > N_NODES) hi = N_NODES;
  int nloc = hi - lo;
  int base = bucket_base[b];
  int end = bucket_base[b + 1];
  cnt[t] = 0; cnt[t + 256] = 0;
  __syncthreads();
  for (int i = base + t; i < end; i += 256)
    atomicAdd(&cnt[(binned[i] & 0xFFFFu) - lo], 1);
  __syncthreads();
  int c0 = cnt[2 * t], c1 = cnt[2 * t + 1];
  int pair = c0 + c1;
  ts[t] = pair;
  __syncthreads();
  for (int off = 1; off < 256; off <<= 1) {
    int v = (t >= off) ? ts[t - off] : 0;
    __syncthreads();
    ts[t] += v;
    __syncthreads();
  }
  int exclp = ts[t] - pair;
  cnt[2 * t] = exclp;
  cnt[2 * t + 1] = exclp + c0;
  if (2 * t < nloc) row_ptr[lo + 2 * t] = base + exclp;
  if (2 * t + 1 < nloc) row_ptr[lo + 2 * t + 1] = base + exclp + c0;
  if (b == NBK - 1 && t == 0) row_ptr[N_NODES] = E_EDGES;
  __syncthreads();
  for (int i = base + t; i < end; i += 256) {
    unsigned int v = binned[i];
    int d = (int)(v & 0xFFFFu) - lo;
    int p = atomicAdd(&cnt[d], 1);
    int s = (int)(v >> 16);
    if (p < STAGE_MAX) staging[p] = s;
    else csr_src[base + p] = s;
  }
  __syncthreads();
  int tot = end - base;
  int lim = tot < STAGE_MAX ? tot : STAGE_MAX;
  for (int k = t; k < lim; k += 256) csr_src[base + k] = staging[k];
}

// ------- layer 0 GEMM via f16 MFMA, fp32 A-load fused convert -------
// wave: 16 rows x 128 cols; A row = lane&15, k-group = lane>>4 (8 contig k)
// D: col = lane&15, row = (lane>>4)*4 + reg
__global__ __launch_bounds__(256) void k_gemm0m(
    const float* __restrict__ x, const _Float16* __restrict__ Wt,
    const float* __restrict__ att_s, const float* __restrict__ att_d,
    _Float16* __restrict__ h, float* __restrict__ a_src, float* __restrict__ a_dst) {
  int lane = threadIdx.x & 63;
  int wv = threadIdx.x >> 6;
  int row0 = blockIdx.x * 64 + wv * 16;
  int m = lane & 15, kg = lane >> 4;
  int arow = row0 + m;
  int arowc = arow < N_NODES ? arow : N_NODES - 1;
  f32x4 acc[8];
#pragma unroll
  for (int ct = 0; ct < 8; ct++) acc[ct] = (f32x4){0.f, 0.f, 0.f, 0.f};
#pragma unroll
  for (int kc = 0; kc < 4; kc++) {
    const float* xp = &x[(size_t)arowc * 128 + kc * 32 + kg * 8];
    float4 xa = *(const float4*)xp;
    float4 xb = *(const float4*)(xp + 4);
    half8 af = {(_Float16)xa.x, (_Float16)xa.y, (_Float16)xa.z, (_Float16)xa.w,
                (_Float16)xb.x, (_Float16)xb.y, (_Float16)xb.z, (_Float16)xb.w};
#pragma unroll
    for (int ct = 0; ct < 8; ct++) {
      half8 bf = *(const half8*)&Wt[(ct * 16 + m) * 128 + kc * 32 + kg * 8];
      acc[ct] = __builtin_amdgcn_mfma_f32_16x16x32_f16(af, bf, acc[ct], 0, 0, 0);
    }
  }
  float as[8], ad[8];
#pragma unroll
  for (int ct = 0; ct < 8; ct++) { as[ct] = att_s[ct * 16 + m]; ad[ct] = att_d[ct * 16 + m]; }
#pragma unroll
  for (int r = 0; r < 4; r++) {
    int row = row0 + kg * 4 + r;
    bool ok = row < N_NODES;
    float ps0 = 0.f, pd0 = 0.f, ps1 = 0.f, pd1 = 0.f;
#pragma unroll
    for (int ct = 0; ct < 4; ct++) { ps0 += acc[ct][r] * as[ct]; pd0 += acc[ct][r] * ad[ct]; }
#pragma unroll
    for (int ct = 4; ct < 8; ct++) { ps1 += acc[ct][r] * as[ct]; pd1 += acc[ct][r] * ad[ct]; }
#pragma unroll
    for (int msk = 1; msk <= 8; msk <<= 1) {
      ps0 += __shfl_xor(ps0, msk); pd0 += __shfl_xor(pd0, msk);
      ps1 += __shfl_xor(ps1, msk); pd1 += __shfl_xor(pd1, msk);
    }
    if (ok) {
#pragma unroll
      for (int ct = 0; ct < 8; ct++)
        h[(size_t)row * 128 + ct * 16 + m] = (_Float16)acc[ct][r];
      if (m == 0) {
        a_src[row * 2 + 0] = ps0; a_dst[row * 2 + 0] = pd0;
        a_src[row * 2 + 1] = ps1; a_dst[row * 2 + 1] = pd1;
      }
    }
  }
}

// ------- layer 1 GEMM via f16 MFMA, BN+ELU fused into A-load -------
__global__ __launch_bounds__(256) void k_gemm1m(
    const float* __restrict__ y, const float* __restrict__ scale,
    const float* __restrict__ shift, const _Float16* __restrict__ Wt,
    const float* __restrict__ att_s, const float* __restrict__ att_d,
    _Float16* __restrict__ h, float* __restrict__ a_src, float* __restrict__ a_dst) {
  int lane = threadIdx.x & 63;
  int wv = threadIdx.x >> 6;
  int row0 = blockIdx.x * 64 + wv * 16;
  int m = lane & 15, kg = lane >> 4;
  int arow = row0 + m;
  int arowc = arow < N_NODES ? arow : N_NODES - 1;
  f32x4 acc[4];
#pragma unroll
  for (int ct = 0; ct < 4; ct++) acc[ct] = (f32x4){0.f, 0.f, 0.f, 0.f};
#pragma unroll
  for (int kc = 0; kc < 4; kc++) {
    int kb = kc * 32 + kg * 8;
    const float* yp = &y[(size_t)arowc * 128 + kb];
    float4 ya = *(const float4*)yp;
    float4 yb = *(const float4*)(yp + 4);
    float4 sa = *(const float4*)&scale[kb], sb = *(const float4*)&scale[kb + 4];
    float4 fa = *(const float4*)&shift[kb], fb = *(const float4*)&shift[kb + 4];
    float v[8];
    v[0] = ya.x * sa.x + fa.x; v[1] = ya.y * sa.y + fa.y;
    v[2] = ya.z * sa.z + fa.z; v[3] = ya.w * sa.w + fa.w;
    v[4] = yb.x * sb.x + fb.x; v[5] = yb.y * sb.y + fb.y;
    v[6] = yb.z * sb.z + fb.z; v[7] = yb.w * sb.w + fb.w;
    half8 af;
#pragma unroll
    for (int j = 0; j < 8; j++) {
      float e = v[j] > 0.f ? v[j] : __expf(v[j]) - 1.f;
      af[j] = (_Float16)e;
    }
#pragma unroll
    for (int ct = 0; ct < 4; ct++) {
      half8 bf = *(const half8*)&Wt[(ct * 16 + m) * 128 + kb];
      acc[ct] = __builtin_amdgcn_mfma_f32_16x16x32_f16(af, bf, acc[ct], 0, 0, 0);
    }
  }
  float as[4], ad[4];
#pragma unroll
  for (int ct = 0; ct < 4; ct++) { as[ct] = att_s[ct * 16 + m]; ad[ct] = att_d[ct * 16 + m]; }
#pragma unroll
  for (int r = 0; r < 4; r++) {
    int row = row0 + kg * 4 + r;
    bool ok = row < N_NODES;
    float ps = 0.f, pd = 0.f;
#pragma unroll
    for (int ct = 0; ct < 4; ct++) { ps += acc[ct][r] * as[ct]; pd += acc[ct][r] * ad[ct]; }
#pragma unroll
    for (int msk = 1; msk <= 8; msk <<= 1) {
      ps += __shfl_xor(ps, msk); pd += __shfl_xor(pd, msk);
    }
    if (ok) {
#pragma unroll
      for (int ct = 0; ct < 4; ct++)
        h[(size_t)row * 64 + ct * 16 + m] = (_Float16)acc[ct][r];
      if (m == 0) { a_src[row] = ps; a_dst[row] = pd; }
    }
  }
}

// ------- layer 0 attention weights: wave per node, EDGE-parallel lanes -------
__global__ __launch_bounds__(256) void k_wts0(
    const int* __restrict__ row_ptr, const int* __restrict__ csr_src,
    const float* __restrict__ a_src, const float* __restrict__ a_dst,
    float2* __restrict__ wts, float2* __restrict__ selfw) {
  int node = (blockIdx.x * blockDim.x + threadIdx.x) >> 6;
  if (node >= N_NODES) return;
  int l = threadIdx.x & 63;
  float ad0 = a_dst[node * 2], ad1 = a_dst[node * 2 + 1];
  float es0 = lrelu(a_src[node * 2] + ad0);
  float es1 = lrelu(a_src[node * 2 + 1] + ad1);
  int beg = row_ptr[node], end = row_ptr[node + 1];
  const float NEGBIG = -3.0e38f;
  float m0 = NEGBIG, s0 = 0.f, m1 = NEGBIG, s1 = 0.f;
  for (int j = beg + l; j < end; j += 64) {
    int s = csr_src[j];
    float e0 = lrelu(a_src[s * 2] + ad0);
    float e1 = lrelu(a_src[s * 2 + 1] + ad1);
    float nm0 = fmaxf(m0, e0);
    s0 = s0 * __expf(m0 - nm0) + __expf(e0 - nm0); m0 = nm0;
    float nm1 = fmaxf(m1, e1);
    s1 = s1 * __expf(m1 - nm1) + __expf(e1 - nm1); m1 = nm1;
  }
#pragma unroll
  for (int msk = 1; msk < 64; msk <<= 1) {
    float om0 = __shfl_xor(m0, msk), os0 = __shfl_xor(s0, msk);
    float nm0 = fmaxf(m0, om0);
    s0 = s0 * __expf(m0 - nm0) + os0 * __expf(om0 - nm0); m0 = nm0;
    float om1 = __shfl_xor(m1, msk), os1 = __shfl_xor(s1, msk);
    float nm1 = fmaxf(m1, om1);
    s1 = s1 * __expf(m1 - nm1) + os1 * __expf(om1 - nm1); m1 = nm1;
  }
  float fm0 = fmaxf(m0, es0);
  float d0 = s0 * __expf(m0 - fm0) + __expf(es0 - fm0);
  float fm1 = fmaxf(m1, es1);
  float d1 = s1 * __expf(m1 - fm1) + __expf(es1 - fm1);
  float inv0 = 1.f / d0, inv1 = 1.f / d1;
  for (int j = beg + l; j < end; j += 64) {
    int s = csr_src[j];
    float e0 = lrelu(a_src[s * 2] + ad0);
    float e1 = lrelu(a_src[s * 2 + 1] + ad1);
    wts[j] = make_float2(__expf(e0 - fm0) * inv0, __expf(e1 - fm1) * inv1);
  }
  if (l == 0) selfw[node] = make_float2(__expf(es0 - fm0) * inv0, __expf(es1 - fm1) * inv1);
}

// ------- layer 0 accumulate: pure FMA over precomputed alphas -------
__global__ __launch_bounds__(256) void k_acc0(
    const int* __restrict__ row_ptr, const int* __restrict__ csr_src,
    const __half* __restrict__ h, const float2* __restrict__ wts,
    const float2* __restrict__ selfw, const float* __restrict__ bias,
    float* __restrict__ out) {
  int node = (blockIdx.x * blockDim.x + threadIdx.x) >> 6;
  if (node >= N_NODES) return;
  int l = threadIdx.x & 63;
  int head = l >> 5;
  int c = l * 2;
  float2 sw = selfw[node];
  float aself = head ? sw.y : sw.x;
  float2 hv = __half22float2(*(const __half2*)&h[(size_t)node * 128 + c]);
  float acc0 = aself * hv.x, acc1 = aself * hv.y;
  float bcc0 = 0.f, bcc1 = 0.f;
  int beg = row_ptr[node], end = row_ptr[node + 1];
  int j = beg;
  for (; j + 4 <= end; j += 4) {
    int s0 = csr_src[j], s1 = csr_src[j + 1], s2 = csr_src[j + 2], s3 = csr_src[j + 3];
    float2 w0 = wts[j], w1 = wts[j + 1], w2 = wts[j + 2], w3 = wts[j + 3];
    float a0 = head ? w0.y : w0.x, a1 = head ? w1.y : w1.x;
    float a2 = head ? w2.y : w2.x, a3 = head ? w3.y : w3.x;
    float2 f0 = __half22float2(*(const __half2*)&h[(size_t)s0 * 128 + c]);
    float2 f1 = __half22float2(*(const __half2*)&h[(size_t)s1 * 128 + c]);
    float2 f2 = __half22float2(*(const __half2*)&h[(size_t)s2 * 128 + c]);
    float2 f3 = __half22float2(*(const __half2*)&h[(size_t)s3 * 128 + c]);
    acc0 += a0 * f0.x + a2 * f2.x;
    bcc0 += a1 * f1.x + a3 * f3.x;
    acc1 += a0 * f0.y + a2 * f2.y;
    bcc1 += a1 * f1.y + a3 * f3.y;
  }
  for (; j < end; j++) {
    int s = csr_src[j];
    float2 w = wts[j];
    float a = head ? w.y : w.x;
    float2 f = __half22float2(*(const __half2*)&h[(size_t)s * 128 + c]);
    acc0 += a * f.x;
    acc1 += a * f.y;
  }
  float2 o;
  o.x = acc0 + bcc0 + bias[c];
  o.y = acc1 + bcc1 + bias[c + 1];
  *(float2*)&out[(size_t)node * 128 + c] = o;
}

// ---------------- BatchNorm stats ----------------
__global__ __launch_bounds__(256) void k_bnstats(const float* __restrict__ x,
                                                 float* __restrict__ bn_sum,
                                                 float* __restrict__ bn_sumsq) {
  int f = threadIdx.x & 127;
  int half = threadIdx.x >> 7;
  float s = 0.f, s2 = 0.f;
  for (int r = blockIdx.x * 2 + half; r < N_NODES; r += gridDim.x * 2) {
    float v = x[(size_t)r * 128 + f];
    s += v;
    s2 += v * v;
  }
  __shared__ float ls[256], ls2[256];
  ls[threadIdx.x] = s;
  ls2[threadIdx.x] = s2;
  __syncthreads();
  if (half == 0) {
    atomicAdd(&bn_sum[f], s + ls[f + 128]);
    atomicAdd(&bn_sumsq[f], s2 + ls2[f + 128]);
  }
}

__global__ void k_bnfinal(const float* __restrict__ sum, const float* __restrict__ sumsq,
                          const float* __restrict__ gamma, const float* __restrict__ beta,
                          float* __restrict__ scale, float* __restrict__ shift) {
  int f = threadIdx.x;
  float mu = sum[f] / (float)N_NODES;
  float var = sumsq[f] / (float)N_NODES - mu * mu;
  float sc = gamma[f] * rsqrtf(var + BN_EPS);
  scale[f] = sc;
  shift[f] = beta[f] - mu * sc;
}

// ------- layer 1 attention weights (1 head) -------
__global__ __launch_bounds__(256) void k_wts1(
    const int* __restrict__ row_ptr, const int* __restrict__ csr_src,
    const float* __restrict__ a_src, const float* __restrict__ a_dst,
    float* __restrict__ wts, float* __restrict__ selfw) {
  int node = (blockIdx.x * blockDim.x + threadIdx.x) >> 6;
  if (node >= N_NODES) return;
  int l = threadIdx.x & 63;
  float ad = a_dst[node];
  float es = lrelu(a_src[node] + ad);
  int beg = row_ptr[node], end = row_ptr[node + 1];
  const float NEGBIG = -3.0e38f;
  float m = NEGBIG, s = 0.f;
  for (int j = beg + l; j < end; j += 64) {
    int sn = csr_src[j];
    float e = lrelu(a_src[sn] + ad);
    float nm = fmaxf(m, e);
    s = s * __expf(m - nm) + __expf(e - nm); m = nm;
  }
#pragma unroll
  for (int msk = 1; msk < 64; msk <<= 1) {
    float om = __shfl_xor(m, msk), os = __shfl_xor(s, msk);
    float nm = fmaxf(m, om);
    s = s * __expf(m - nm) + os * __expf(om - nm); m = nm;
  }
  float fm = fmaxf(m, es);
  float d = s * __expf(m - fm) + __expf(es - fm);
  float inv = 1.f / d;
  for (int j = beg + l; j < end; j += 64) {
    int sn = csr_src[j];
    float e = lrelu(a_src[sn] + ad);
    wts[j] = __expf(e - fm) * inv;
  }
  if (l == 0) selfw[node] = __expf(es - fm) * inv;
}

// ------- layer 1 accumulate -------
__global__ __launch_bounds__(256) void k_acc1(
    const int* __restrict__ row_ptr, const int* __restrict__ csr_src,
    const __half* __restrict__ h, const float* __restrict__ wts,
    const float* __restrict__ selfw, const float* __restrict__ bias,
    float* __restrict__ out) {
  int node = (blockIdx.x * blockDim.x + threadIdx.x) >> 6;
  if (node >= N_NODES) return;
  int l = threadIdx.x & 63;
  float acc = selfw[node] * __half2float(h[(size_t)node * 64 + l]);
  float bcc = 0.f;
  int beg = row_ptr[node], end = row_ptr[node + 1];
  int j = beg;
  for (; j + 4 <= end; j += 4) {
    int s0 = csr_src[j], s1 = csr_src[j + 1], s2 = csr_src[j + 2], s3 = csr_src[j + 3];
    float a0 = wts[j], a1 = wts[j + 1], a2 = wts[j + 2], a3 = wts[j + 3];
    float f0 = __half2float(h[(size_t)s0 * 64 + l]);
    float f1 = __half2float(h[(size_t)s1 * 64 + l]);
    float f2 = __half2float(h[(size_t)s2 * 64 + l]);
    float f3 = __half2float(h[(size_t)s3 * 64 + l]);
    acc += a0 * f0 + a2 * f2;
    bcc += a1 * f1 + a3 * f3;
  }
  for (; j < end; j++) {
    int s = csr_src[j];
    acc += wts[j] * __half2float(h[(size_t)s * 64 + l]);
  }
  out[(size_t)node * 64 + l] = acc + bcc + bias[l];
}

// ---------------- launch ----------------
extern "C" void kernel_launch(void* const* d_in, const int* in_sizes, int n_in,
                              void* d_out, int out_size, void* d_ws, size_t ws_size,
                              hipStream_t stream) {
  const float* data = (const float*)d_in[0];
  const int* ei = (const int*)d_in[1];
  const float* W0 = (const float*)d_in[2];
  const float* att_src0 = (const float*)d_in[3];
  const float* att_dst0 = (const float*)d_in[4];
  const float* bias0 = (const float*)d_in[5];
  const float* gamma0 = (const float*)d_in[6];
  const float* beta0 = (const float*)d_in[7];
  const float* W1 = (const float*)d_in[8];
  const float* att_src1 = (const float*)d_in[9];
  const float* att_dst1 = (const float*)d_in[10];
  const float* bias1 = (const float*)d_in[11];
  float* out = (float*)d_out;

  char* ws = (char*)d_ws;
  size_t off = 0;
  auto alloc = [&](size_t bytes) -> void* {
    void* p = ws + off;
    off = (off + bytes + 255) & ~(size_t)255;
    return p;
  };
  int* cnt = (int*)alloc((size_t)CNT_N * 4);
  int* tmp = (int*)alloc((size_t)CNT_N * 4);
  int* bsums = (int*)alloc(32 * 4);
  int* bucket_base = (int*)alloc((NBK + 1) * 4);
  int* row_ptr = (int*)alloc((N_NODES + 1) * 4);
  unsigned int* binned = (unsigned int*)alloc((size_t)E_EDGES * 4);
  int* csr_src = (int*)alloc((size_t)E_EDGES * 4);
  _Float16* W0t = (_Float16*)alloc(128 * 128 * 2);
  _Float16* W1t = (_Float16*)alloc(64 * 128 * 2);
  _Float16* h0 = (_Float16*)alloc((size_t)N_NODES * 128 * 2);
  float* a_s0 = (float*)alloc((size_t)N_NODES * 2 * 4);
  float* a_d0 = (float*)alloc((size_t)N_NODES * 2 * 4);
  float2* wts0 = (float2*)alloc((size_t)E_EDGES * 8);
  float2* selfw0 = (float2*)alloc((size_t)N_NODES * 8);
  float* out0 = (float*)alloc((size_t)N_NODES * 128 * 4);
  float* bn_sum = (float*)alloc(128 * 4);
  float* bn_sumsq = (float*)alloc(128 * 4);
  float* bn_scale = (float*)alloc(128 * 4);
  float* bn_shift = (float*)alloc(128 * 4);
  _Float16* h1 = h0;               // alias: h0 dead after acc0
  float* a_s1 = a_s0;
  float* a_d1 = a_d0;
  float* wts1 = (float*)wts0;      // alias: wts0 dead after acc0
  float* selfw1 = (float*)selfw0;

  const int* srcArr = ei;
  const int* dstArr = ei + E_EDGES;

  k_zero<<<1, 128, 0, stream>>>(bn_sum, bn_sumsq);
  k_cvtW<<<1, 256, 0, stream>>>(W0, W1, W0t, W1t);
  k_l1hist<<<L1_BLOCKS, 256, 0, stream>>>(dstArr, cnt);
  k_scan1g<<<SCG_BLOCKS, 256, 0, stream>>>(cnt, tmp, bsums);
  k_scan2g<<<1, 64, 0, stream>>>(bsums);
  k_l1scatter<<<L1_BLOCKS, 256, 0, stream>>>(srcArr, dstArr, tmp, bsums, binned);
  k_bbase<<<1, 128, 0, stream>>>(tmp, bsums, bucket_base);
  k_scatter3<<<NBK, 256, 0, stream>>>(bucket_base, binned, row_ptr, csr_src);
  k_gemm0m<<<(N_NODES + 63) / 64, 256, 0, stream>>>(data, W0t, att_src0, att_dst0, h0, a_s0,
                                                    a_d0);
  k_wts0<<<(N_NODES + 3) / 4, 256, 0, stream>>>(row_ptr, csr_src, a_s0, a_d0, wts0, selfw0);
  k_acc0<<<(N_NODES + 3) / 4, 256, 0, stream>>>(row_ptr, csr_src, (const __half*)h0, wts0,
                                                selfw0, bias0, out0);
  k_bnstats<<<1024, 256, 0, stream>>>(out0, bn_sum, bn_sumsq);
  k_bnfinal<<<1, 128, 0, stream>>>(bn_sum, bn_sumsq, gamma0, beta0, bn_scale, bn_shift);
  k_gemm1m<<<(N_NODES + 63) / 64, 256, 0, stream>>>(out0, bn_scale, bn_shift, W1t, att_src1,
                                                    att_dst1, h1, a_s1, a_d1);
  k_wts1<<<(N_NODES + 3) / 4, 256, 0, stream>>>(row_ptr, csr_src, a_s1, a_d1, wts1, selfw1);
  k_acc1<<<(N_NODES + 3) / 4, 256, 0, stream>>>(row_ptr, csr_src, (const __half*)h1, wts1,
                                                selfw1, bias1, out);
}

// Round 10
// 330.327 us; speedup vs baseline: 1.0456x; 1.0456x over previous
//
#include <hip/hip_runtime.h>
#include <hip/hip_fp16.h>
#include <math.h>

#define N_NODES 50000
#define E_EDGES 800000
#define NEG_SLOPE 0.2f
#define BN_EPS 1e-5f

#define BK_SHIFT 9                       // 512-node buckets
#define NBK 98                           // ceil(50000/512)
#define L1_BLOCKS 256
#define L1_CHUNK (E_EDGES / L1_BLOCKS)   // 3125 exactly
#define CNT_N (NBK * L1_BLOCKS)          // 25088
#define SCG_BLOCKS ((CNT_N + 1023) / 1024)  // 25
#define STAGE_MAX 9216                   // per-bucket staging

typedef __attribute__((ext_vector_type(8))) _Float16 half8;
typedef __attribute__((ext_vector_type(4))) float f32x4;

__device__ __forceinline__ float lrelu(float v) { return v > 0.f ? v : NEG_SLOPE * v; }

// ---------------- init (BN accumulators only) ----------------
__global__ void k_zero(float* __restrict__ bn_sum, float* __restrict__ bn_sumsq) {
  int t = threadIdx.x;
  if (t < 128) { bn_sum[t] = 0.f; bn_sumsq[t] = 0.f; }
}

// ---------------- fp16 weight transpose-converts ----------------
__global__ void k_cvtW(const float* __restrict__ W0, const float* __restrict__ W1,
                       _Float16* __restrict__ W0t, _Float16* __restrict__ W1t) {
  int t = threadIdx.x;
  for (int idx = t; idx < 128 * 128; idx += 256) {
    int k = idx >> 7, c = idx & 127;
    W0t[c * 128 + k] = (_Float16)W0[idx];
  }
  for (int idx = t; idx < 128 * 64; idx += 256) {
    int k = idx >> 6, c = idx & 63;
    W1t[c * 128 + k] = (_Float16)W1[idx];
  }
}

// ---- L1: per-block bucket histogram ----
__global__ __launch_bounds__(256) void k_l1hist(const int* __restrict__ dst,
                                                int* __restrict__ cnt) {
  __shared__ int lcnt[NBK];
  int t = threadIdx.x;
  if (t < NBK) lcnt[t] = 0;
  __syncthreads();
  int beg = blockIdx.x * L1_CHUNK, end = beg + L1_CHUNK;
  for (int e = beg + t; e < end; e += 256)
    atomicAdd(&lcnt[((unsigned int)dst[e]) >> BK_SHIFT], 1);
  __syncthreads();
  for (int b = t; b < NBK; b += 256) cnt[b * L1_BLOCKS + blockIdx.x] = lcnt[b];
}

// ---- hierarchical exclusive scan over CNT_N ----
__global__ __launch_bounds__(256) void k_scan1g(const int* __restrict__ cnt,
                                                int* __restrict__ tmp,
                                                int* __restrict__ bsums) {
  __shared__ int ts[256];
  int t = threadIdx.x;
  int base = blockIdx.x * 1024 + t * 4;
  int c0 = (base + 0 < CNT_N) ? cnt[base + 0] : 0;
  int c1 = (base + 1 < CNT_N) ? cnt[base + 1] : 0;
  int c2 = (base + 2 < CNT_N) ? cnt[base + 2] : 0;
  int c3 = (base + 3 < CNT_N) ? cnt[base + 3] : 0;
  int s = c0 + c1 + c2 + c3;
  ts[t] = s;
  __syncthreads();
  for (int off = 1; off < 256; off <<= 1) {
    int v = (t >= off) ? ts[t - off] : 0;
    __syncthreads();
    ts[t] += v;
    __syncthreads();
  }
  int excl = ts[t] - s;
  if (t == 255) bsums[blockIdx.x] = ts[255];
  if (base + 0 < CNT_N) tmp[base + 0] = excl;
  if (base + 1 < CNT_N) tmp[base + 1] = excl + c0;
  if (base + 2 < CNT_N) tmp[base + 2] = excl + c0 + c1;
  if (base + 3 < CNT_N) tmp[base + 3] = excl + c0 + c1 + c2;
}

__global__ void k_scan2g(int* __restrict__ bsums) {
  int t = threadIdx.x;
  int orig = (t < SCG_BLOCKS) ? bsums[t] : 0;
  int v = orig;
#pragma unroll
  for (int off = 1; off < 64; off <<= 1) {
    int u = __shfl_up(v, off);
    if (t >= off) v += u;
  }
  if (t < SCG_BLOCKS) bsums[t] = v - orig;
}

// ---- L1 scatter: deterministic bases per (bucket,block) ----
__global__ __launch_bounds__(256) void k_l1scatter(const int* __restrict__ src,
                                                   const int* __restrict__ dst,
                                                   const int* __restrict__ tmp,
                                                   const int* __restrict__ bsums,
                                                   unsigned int* __restrict__ binned) {
  __shared__ int cur[NBK];
  int t = threadIdx.x;
  for (int b = t; b < NBK; b += 256) {
    int idx = b * L1_BLOCKS + blockIdx.x;
    cur[b] = tmp[idx] + bsums[idx >> 10];
  }
  __syncthreads();
  int beg = blockIdx.x * L1_CHUNK, end = beg + L1_CHUNK;
  for (int e = beg + t; e < end; e += 256) {
    unsigned int d = (unsigned int)dst[e];
    int b = d >> BK_SHIFT;
    int p = atomicAdd(&cur[b], 1);
    binned[p] = ((unsigned int)src[e] << 16) | d;
  }
}

__global__ void k_bbase(const int* __restrict__ tmp, const int* __restrict__ bsums,
                        int* __restrict__ bucket_base) {
  int b = threadIdx.x;
  if (b < NBK) {
    int idx = b * L1_BLOCKS;
    bucket_base[b] = tmp[idx] + bsums[idx >> 10];
  }
  if (b == NBK) bucket_base[NBK] = E_EDGES;
}

// ---- L2: per-bucket LDS counting sort ----
__global__ __launch_bounds__(256) void k_scatter3(const int* __restrict__ bucket_base,
                                                  const unsigned int* __restrict__ binned,
                                                  int* __restrict__ row_ptr,
                                                  int* __restrict__ csr_src) {
  __shared__ int cnt[512];
  __shared__ int staging[STAGE_MAX];
  __shared__ int ts[256];
  int t = threadIdx.x;
  int b = blockIdx.x;
  int lo = b << BK_SHIFT;
  int hi = lo + 512; if (hi > N_NODES) hi = N_NODES;
  int nloc = hi - lo;
  int base = bucket_base[b];
  int end = bucket_base[b + 1];
  cnt[t] = 0; cnt[t + 256] = 0;
  __syncthreads();
  for (int i = base + t; i < end; i += 256)
    atomicAdd(&cnt[(binned[i] & 0xFFFFu) - lo], 1);
  __syncthreads();
  int c0 = cnt[2 * t], c1 = cnt[2 * t + 1];
  int pair = c0 + c1;
  ts[t] = pair;
  __syncthreads();
  for (int off = 1; off < 256; off <<= 1) {
    int v = (t >= off) ? ts[t - off] : 0;
    __syncthreads();
    ts[t] += v;
    __syncthreads();
  }
  int exclp = ts[t] - pair;
  cnt[2 * t] = exclp;
  cnt[2 * t + 1] = exclp + c0;
  if (2 * t < nloc) row_ptr[lo + 2 * t] = base + exclp;
  if (2 * t + 1 < nloc) row_ptr[lo + 2 * t + 1] = base + exclp + c0;
  if (b == NBK - 1 && t == 0) row_ptr[N_NODES] = E_EDGES;
  __syncthreads();
  for (int i = base + t; i < end; i += 256) {
    unsigned int v = binned[i];
    int d = (int)(v & 0xFFFFu) - lo;
    int p = atomicAdd(&cnt[d], 1);
    int s = (int)(v >> 16);
    if (p < STAGE_MAX) staging[p] = s;
    else csr_src[base + p] = s;
  }
  __syncthreads();
  int tot = end - base;
  int lim = tot < STAGE_MAX ? tot : STAGE_MAX;
  for (int k = t; k < lim; k += 256) csr_src[base + k] = staging[k];
}

// ------- layer 0 GEMM via f16 MFMA, fp32 A-load fused convert -------
__global__ __launch_bounds__(256) void k_gemm0m(
    const float* __restrict__ x, const _Float16* __restrict__ Wt,
    const float* __restrict__ att_s, const float* __restrict__ att_d,
    _Float16* __restrict__ h, float* __restrict__ a_src, float* __restrict__ a_dst) {
  int lane = threadIdx.x & 63;
  int wv = threadIdx.x >> 6;
  int row0 = blockIdx.x * 64 + wv * 16;
  int m = lane & 15, kg = lane >> 4;
  int arow = row0 + m;
  int arowc = arow < N_NODES ? arow : N_NODES - 1;
  f32x4 acc[8];
#pragma unroll
  for (int ct = 0; ct < 8; ct++) acc[ct] = (f32x4){0.f, 0.f, 0.f, 0.f};
#pragma unroll
  for (int kc = 0; kc < 4; kc++) {
    const float* xp = &x[(size_t)arowc * 128 + kc * 32 + kg * 8];
    float4 xa = *(const float4*)xp;
    float4 xb = *(const float4*)(xp + 4);
    half8 af = {(_Float16)xa.x, (_Float16)xa.y, (_Float16)xa.z, (_Float16)xa.w,
                (_Float16)xb.x, (_Float16)xb.y, (_Float16)xb.z, (_Float16)xb.w};
#pragma unroll
    for (int ct = 0; ct < 8; ct++) {
      half8 bf = *(const half8*)&Wt[(ct * 16 + m) * 128 + kc * 32 + kg * 8];
      acc[ct] = __builtin_amdgcn_mfma_f32_16x16x32_f16(af, bf, acc[ct], 0, 0, 0);
    }
  }
  float as[8], ad[8];
#pragma unroll
  for (int ct = 0; ct < 8; ct++) { as[ct] = att_s[ct * 16 + m]; ad[ct] = att_d[ct * 16 + m]; }
#pragma unroll
  for (int r = 0; r < 4; r++) {
    int row = row0 + kg * 4 + r;
    bool ok = row < N_NODES;
    float ps0 = 0.f, pd0 = 0.f, ps1 = 0.f, pd1 = 0.f;
#pragma unroll
    for (int ct = 0; ct < 4; ct++) { ps0 += acc[ct][r] * as[ct]; pd0 += acc[ct][r] * ad[ct]; }
#pragma unroll
    for (int ct = 4; ct < 8; ct++) { ps1 += acc[ct][r] * as[ct]; pd1 += acc[ct][r] * ad[ct]; }
#pragma unroll
    for (int msk = 1; msk <= 8; msk <<= 1) {
      ps0 += __shfl_xor(ps0, msk); pd0 += __shfl_xor(pd0, msk);
      ps1 += __shfl_xor(ps1, msk); pd1 += __shfl_xor(pd1, msk);
    }
    if (ok) {
#pragma unroll
      for (int ct = 0; ct < 8; ct++)
        h[(size_t)row * 128 + ct * 16 + m] = (_Float16)acc[ct][r];
      if (m == 0) {
        a_src[row * 2 + 0] = ps0; a_dst[row * 2 + 0] = pd0;
        a_src[row * 2 + 1] = ps1; a_dst[row * 2 + 1] = pd1;
      }
    }
  }
}

// ------- layer 1 GEMM via f16 MFMA, BN+ELU fused into A-load -------
__global__ __launch_bounds__(256) void k_gemm1m(
    const float* __restrict__ y, const float* __restrict__ scale,
    const float* __restrict__ shift, const _Float16* __restrict__ Wt,
    const float* __restrict__ att_s, const float* __restrict__ att_d,
    _Float16* __restrict__ h, float* __restrict__ a_src, float* __restrict__ a_dst) {
  int lane = threadIdx.x & 63;
  int wv = threadIdx.x >> 6;
  int row0 = blockIdx.x * 64 + wv * 16;
  int m = lane & 15, kg = lane >> 4;
  int arow = row0 + m;
  int arowc = arow < N_NODES ? arow : N_NODES - 1;
  f32x4 acc[4];
#pragma unroll
  for (int ct = 0; ct < 4; ct++) acc[ct] = (f32x4){0.f, 0.f, 0.f, 0.f};
#pragma unroll
  for (int kc = 0; kc < 4; kc++) {
    int kb = kc * 32 + kg * 8;
    const float* yp = &y[(size_t)arowc * 128 + kb];
    float4 ya = *(const float4*)yp;
    float4 yb = *(const float4*)(yp + 4);
    float4 sa = *(const float4*)&scale[kb], sb = *(const float4*)&scale[kb + 4];
    float4 fa = *(const float4*)&shift[kb], fb = *(const float4*)&shift[kb + 4];
    float v[8];
    v[0] = ya.x * sa.x + fa.x; v[1] = ya.y * sa.y + fa.y;
    v[2] = ya.z * sa.z + fa.z; v[3] = ya.w * sa.w + fa.w;
    v[4] = yb.x * sb.x + fb.x; v[5] = yb.y * sb.y + fb.y;
    v[6] = yb.z * sb.z + fb.z; v[7] = yb.w * sb.w + fb.w;
    half8 af;
#pragma unroll
    for (int j = 0; j < 8; j++) {
      float e = v[j] > 0.f ? v[j] : __expf(v[j]) - 1.f;
      af[j] = (_Float16)e;
    }
#pragma unroll
    for (int ct = 0; ct < 4; ct++) {
      half8 bf = *(const half8*)&Wt[(ct * 16 + m) * 128 + kb];
      acc[ct] = __builtin_amdgcn_mfma_f32_16x16x32_f16(af, bf, acc[ct], 0, 0, 0);
    }
  }
  float as[4], ad[4];
#pragma unroll
  for (int ct = 0; ct < 4; ct++) { as[ct] = att_s[ct * 16 + m]; ad[ct] = att_d[ct * 16 + m]; }
#pragma unroll
  for (int r = 0; r < 4; r++) {
    int row = row0 + kg * 4 + r;
    bool ok = row < N_NODES;
    float ps = 0.f, pd = 0.f;
#pragma unroll
    for (int ct = 0; ct < 4; ct++) { ps += acc[ct][r] * as[ct]; pd += acc[ct][r] * ad[ct]; }
#pragma unroll
    for (int msk = 1; msk <= 8; msk <<= 1) {
      ps += __shfl_xor(ps, msk); pd += __shfl_xor(pd, msk);
    }
    if (ok) {
#pragma unroll
      for (int ct = 0; ct < 4; ct++)
        h[(size_t)row * 64 + ct * 16 + m] = (_Float16)acc[ct][r];
      if (m == 0) { a_src[row] = ps; a_dst[row] = pd; }
    }
  }
}

// ------- layer 0 attention weights: wave per node, EDGE-parallel lanes (half2 out) -------
__global__ __launch_bounds__(256) void k_wts0(
    const int* __restrict__ row_ptr, const int* __restrict__ csr_src,
    const float* __restrict__ a_src, const float* __restrict__ a_dst,
    __half2* __restrict__ wts, float2* __restrict__ selfw) {
  int node = (blockIdx.x * blockDim.x + threadIdx.x) >> 6;
  if (node >= N_NODES) return;
  int l = threadIdx.x & 63;
  float ad0 = a_dst[node * 2], ad1 = a_dst[node * 2 + 1];
  float es0 = lrelu(a_src[node * 2] + ad0);
  float es1 = lrelu(a_src[node * 2 + 1] + ad1);
  int beg = row_ptr[node], end = row_ptr[node + 1];
  const float NEGBIG = -3.0e38f;
  float m0 = NEGBIG, s0 = 0.f, m1 = NEGBIG, s1 = 0.f;
  for (int j = beg + l; j < end; j += 64) {
    int s = csr_src[j];
    float e0 = lrelu(a_src[s * 2] + ad0);
    float e1 = lrelu(a_src[s * 2 + 1] + ad1);
    float nm0 = fmaxf(m0, e0);
    s0 = s0 * __expf(m0 - nm0) + __expf(e0 - nm0); m0 = nm0;
    float nm1 = fmaxf(m1, e1);
    s1 = s1 * __expf(m1 - nm1) + __expf(e1 - nm1); m1 = nm1;
  }
#pragma unroll
  for (int msk = 1; msk < 64; msk <<= 1) {
    float om0 = __shfl_xor(m0, msk), os0 = __shfl_xor(s0, msk);
    float nm0 = fmaxf(m0, om0);
    s0 = s0 * __expf(m0 - nm0) + os0 * __expf(om0 - nm0); m0 = nm0;
    float om1 = __shfl_xor(m1, msk), os1 = __shfl_xor(s1, msk);
    float nm1 = fmaxf(m1, om1);
    s1 = s1 * __expf(m1 - nm1) + os1 * __expf(om1 - nm1); m1 = nm1;
  }
  float fm0 = fmaxf(m0, es0);
  float d0 = s0 * __expf(m0 - fm0) + __expf(es0 - fm0);
  float fm1 = fmaxf(m1, es1);
  float d1 = s1 * __expf(m1 - fm1) + __expf(es1 - fm1);
  float inv0 = 1.f / d0, inv1 = 1.f / d1;
  for (int j = beg + l; j < end; j += 64) {
    int s = csr_src[j];
    float e0 = lrelu(a_src[s * 2] + ad0);
    float e1 = lrelu(a_src[s * 2 + 1] + ad1);
    wts[j] = __floats2half2_rn(__expf(e0 - fm0) * inv0, __expf(e1 - fm1) * inv1);
  }
  if (l == 0) selfw[node] = make_float2(__expf(es0 - fm0) * inv0, __expf(es1 - fm1) * inv1);
}

// ------- layer 0 accumulate: 16 channel-lanes x 4 edge-ways, half8 gathers -------
__global__ __launch_bounds__(256) void k_acc0(
    const int* __restrict__ row_ptr, const int* __restrict__ csr_src,
    const _Float16* __restrict__ h, const __half2* __restrict__ wts,
    const float2* __restrict__ selfw, const float* __restrict__ bias,
    float* __restrict__ out) {
  int node = (blockIdx.x * blockDim.x + threadIdx.x) >> 6;
  if (node >= N_NODES) return;
  int l = threadIdx.x & 63;
  int cl = l & 15, ew = l >> 4;
  int cbase = cl * 8;
  int head = cl >> 3;
  float acc[8];
#pragma unroll
  for (int k = 0; k < 8; k++) acc[k] = 0.f;
  int beg = row_ptr[node], end = row_ptr[node + 1];
  if (ew == 0) {  // self contribution on way 0
    float2 sw = selfw[node];
    float a = head ? sw.y : sw.x;
    half8 hv = *(const half8*)&h[(size_t)node * 128 + cbase];
#pragma unroll
    for (int k = 0; k < 8; k++) acc[k] += a * (float)hv[k];
  }
  int j = beg + ew;
  for (; j + 4 < end; j += 8) {  // 2x unroll: 8 edges in flight per wave
    int s0 = csr_src[j], s1 = csr_src[j + 4];
    __half2 w0 = wts[j], w1 = wts[j + 4];
    half8 h0v = *(const half8*)&h[(size_t)s0 * 128 + cbase];
    half8 h1v = *(const half8*)&h[(size_t)s1 * 128 + cbase];
    float a0 = head ? __high2float(w0) : __low2float(w0);
    float a1 = head ? __high2float(w1) : __low2float(w1);
#pragma unroll
    for (int k = 0; k < 8; k++) acc[k] += a0 * (float)h0v[k] + a1 * (float)h1v[k];
  }
  if (j < end) {
    int s0 = csr_src[j];
    __half2 w0 = wts[j];
    half8 h0v = *(const half8*)&h[(size_t)s0 * 128 + cbase];
    float a0 = head ? __high2float(w0) : __low2float(w0);
#pragma unroll
    for (int k = 0; k < 8; k++) acc[k] += a0 * (float)h0v[k];
  }
#pragma unroll
  for (int k = 0; k < 8; k++) {
    acc[k] += __shfl_xor(acc[k], 16);
    acc[k] += __shfl_xor(acc[k], 32);
  }
  if (ew == 0) {
    float4 b0 = *(const float4*)&bias[cbase];
    float4 b1 = *(const float4*)&bias[cbase + 4];
    float4 o0 = make_float4(acc[0] + b0.x, acc[1] + b0.y, acc[2] + b0.z, acc[3] + b0.w);
    float4 o1 = make_float4(acc[4] + b1.x, acc[5] + b1.y, acc[6] + b1.z, acc[7] + b1.w);
    *(float4*)&out[(size_t)node * 128 + cbase] = o0;
    *(float4*)&out[(size_t)node * 128 + cbase + 4] = o1;
  }
}

// ---------------- BatchNorm stats ----------------
__global__ __launch_bounds__(256) void k_bnstats(const float* __restrict__ x,
                                                 float* __restrict__ bn_sum,
                                                 float* __restrict__ bn_sumsq) {
  int f = threadIdx.x & 127;
  int half = threadIdx.x >> 7;
  float s = 0.f, s2 = 0.f;
  for (int r = blockIdx.x * 2 + half; r < N_NODES; r += gridDim.x * 2) {
    float v = x[(size_t)r * 128 + f];
    s += v;
    s2 += v * v;
  }
  __shared__ float ls[256], ls2[256];
  ls[threadIdx.x] = s;
  ls2[threadIdx.x] = s2;
  __syncthreads();
  if (half == 0) {
    atomicAdd(&bn_sum[f], s + ls[f + 128]);
    atomicAdd(&bn_sumsq[f], s2 + ls2[f + 128]);
  }
}

__global__ void k_bnfinal(const float* __restrict__ sum, const float* __restrict__ sumsq,
                          const float* __restrict__ gamma, const float* __restrict__ beta,
                          float* __restrict__ scale, float* __restrict__ shift) {
  int f = threadIdx.x;
  float mu = sum[f] / (float)N_NODES;
  float var = sumsq[f] / (float)N_NODES - mu * mu;
  float sc = gamma[f] * rsqrtf(var + BN_EPS);
  scale[f] = sc;
  shift[f] = beta[f] - mu * sc;
}

// ------- layer 1 attention weights (1 head, half out) -------
__global__ __launch_bounds__(256) void k_wts1(
    const int* __restrict__ row_ptr, const int* __restrict__ csr_src,
    const float* __restrict__ a_src, const float* __restrict__ a_dst,
    __half* __restrict__ wts, float* __restrict__ selfw) {
  int node = (blockIdx.x * blockDim.x + threadIdx.x) >> 6;
  if (node >= N_NODES) return;
  int l = threadIdx.x & 63;
  float ad = a_dst[node];
  float es = lrelu(a_src[node] + ad);
  int beg = row_ptr[node], end = row_ptr[node + 1];
  const float NEGBIG = -3.0e38f;
  float m = NEGBIG, s = 0.f;
  for (int j = beg + l; j < end; j += 64) {
    int sn = csr_src[j];
    float e = lrelu(a_src[sn] + ad);
    float nm = fmaxf(m, e);
    s = s * __expf(m - nm) + __expf(e - nm); m = nm;
  }
#pragma unroll
  for (int msk = 1; msk < 64; msk <<= 1) {
    float om = __shfl_xor(m, msk), os = __shfl_xor(s, msk);
    float nm = fmaxf(m, om);
    s = s * __expf(m - nm) + os * __expf(om - nm); m = nm;
  }
  float fm = fmaxf(m, es);
  float d = s * __expf(m - fm) + __expf(es - fm);
  float inv = 1.f / d;
  for (int j = beg + l; j < end; j += 64) {
    int sn = csr_src[j];
    float e = lrelu(a_src[sn] + ad);
    wts[j] = __float2half_rn(__expf(e - fm) * inv);
  }
  if (l == 0) selfw[node] = __expf(es - fm) * inv;
}

// ------- layer 1 accumulate: 8 channel-lanes x 8 edge-ways, half8 gathers -------
__global__ __launch_bounds__(256) void k_acc1(
    const int* __restrict__ row_ptr, const int* __restrict__ csr_src,
    const _Float16* __restrict__ h, const __half* __restrict__ wts,
    const float* __restrict__ selfw, const float* __restrict__ bias,
    float* __restrict__ out) {
  int node = (blockIdx.x * blockDim.x + threadIdx.x) >> 6;
  if (node >= N_NODES) return;
  int l = threadIdx.x & 63;
  int cl = l & 7, ew = l >> 3;
  int cbase = cl * 8;
  float acc[8];
#pragma unroll
  for (int k = 0; k < 8; k++) acc[k] = 0.f;
  int beg = row_ptr[node], end = row_ptr[node + 1];
  if (ew == 0) {
    float a = selfw[node];
    half8 hv = *(const half8*)&h[(size_t)node * 64 + cbase];
#pragma unroll
    for (int k = 0; k < 8; k++) acc[k] += a * (float)hv[k];
  }
  int j = beg + ew;
  for (; j + 8 < end; j += 16) {  // 2x unroll: 16 edges in flight per wave
    int s0 = csr_src[j], s1 = csr_src[j + 8];
    float a0 = __half2float(wts[j]), a1 = __half2float(wts[j + 8]);
    half8 h0v = *(const half8*)&h[(size_t)s0 * 64 + cbase];
    half8 h1v = *(const half8*)&h[(size_t)s1 * 64 + cbase];
#pragma unroll
    for (int k = 0; k < 8; k++) acc[k] += a0 * (float)h0v[k] + a1 * (float)h1v[k];
  }
  if (j < end) {
    int s0 = csr_src[j];
    float a0 = __half2float(wts[j]);
    half8 h0v = *(const half8*)&h[(size_t)s0 * 64 + cbase];
#pragma unroll
    for (int k = 0; k < 8; k++) acc[k] += a0 * (float)h0v[k];
  }
#pragma unroll
  for (int k = 0; k < 8; k++) {
    acc[k] += __shfl_xor(acc[k], 8);
    acc[k] += __shfl_xor(acc[k], 16);
    acc[k] += __shfl_xor(acc[k], 32);
  }
  if (ew == 0) {
    float4 b0 = *(const float4*)&bias[cbase];
    float4 b1 = *(const float4*)&bias[cbase + 4];
    float4 o0 = make_float4(acc[0] + b0.x, acc[1] + b0.y, acc[2] + b0.z, acc[3] + b0.w);
    float4 o1 = make_float4(acc[4] + b1.x, acc[5] + b1.y, acc[6] + b1.z, acc[7] + b1.w);
    *(float4*)&out[(size_t)node * 64 + cbase] = o0;
    *(float4*)&out[(size_t)node * 64 + cbase + 4] = o1;
  }
}

// ---------------- launch ----------------
extern "C" void kernel_launch(void* const* d_in, const int* in_sizes, int n_in,
                              void* d_out, int out_size, void* d_ws, size_t ws_size,
                              hipStream_t stream) {
  const float* data = (const float*)d_in[0];
  const int* ei = (const int*)d_in[1];
  const float* W0 = (const float*)d_in[2];
  const float* att_src0 = (const float*)d_in[3];
  const float* att_dst0 = (const float*)d_in[4];
  const float* bias0 = (const float*)d_in[5];
  const float* gamma0 = (const float*)d_in[6];
  const float* beta0 = (const float*)d_in[7];
  const float* W1 = (const float*)d_in[8];
  const float* att_src1 = (const float*)d_in[9];
  const float* att_dst1 = (const float*)d_in[10];
  const float* bias1 = (const float*)d_in[11];
  float* out = (float*)d_out;

  char* ws = (char*)d_ws;
  size_t off = 0;
  auto alloc = [&](size_t bytes) -> void* {
    void* p = ws + off;
    off = (off + bytes + 255) & ~(size_t)255;
    return p;
  };
  int* cnt = (int*)alloc((size_t)CNT_N * 4);
  int* tmp = (int*)alloc((size_t)CNT_N * 4);
  int* bsums = (int*)alloc(32 * 4);
  int* bucket_base = (int*)alloc((NBK + 1) * 4);
  int* row_ptr = (int*)alloc((N_NODES + 1) * 4);
  unsigned int* binned = (unsigned int*)alloc((size_t)E_EDGES * 4);
  int* csr_src = (int*)alloc((size_t)E_EDGES * 4);
  _Float16* W0t = (_Float16*)alloc(128 * 128 * 2);
  _Float16* W1t = (_Float16*)alloc(64 * 128 * 2);
  _Float16* h0 = (_Float16*)alloc((size_t)N_NODES * 128 * 2);
  float* a_s0 = (float*)alloc((size_t)N_NODES * 2 * 4);
  float* a_d0 = (float*)alloc((size_t)N_NODES * 2 * 4);
  __half2* wts0 = (__half2*)alloc((size_t)E_EDGES * 4);
  float2* selfw0 = (float2*)alloc((size_t)N_NODES * 8);
  float* out0 = (float*)alloc((size_t)N_NODES * 128 * 4);
  float* bn_sum = (float*)alloc(128 * 4);
  float* bn_sumsq = (float*)alloc(128 * 4);
  float* bn_scale = (float*)alloc(128 * 4);
  float* bn_shift = (float*)alloc(128 * 4);
  _Float16* h1 = h0;                 // alias: h0 dead after acc0
  float* a_s1 = a_s0;
  float* a_d1 = a_d0;
  __half* wts1 = (__half*)wts0;      // alias: wts0 dead after acc0
  float* selfw1 = (float*)selfw0;

  const int* srcArr = ei;
  const int* dstArr = ei + E_EDGES;

  k_zero<<<1, 128, 0, stream>>>(bn_sum, bn_sumsq);
  k_cvtW<<<1, 256, 0, stream>>>(W0, W1, W0t, W1t);
  k_l1hist<<<L1_BLOCKS, 256, 0, stream>>>(dstArr, cnt);
  k_scan1g<<<SCG_BLOCKS, 256, 0, stream>>>(cnt, tmp, bsums);
  k_scan2g<<<1, 64, 0, stream>>>(bsums);
  k_l1scatter<<<L1_BLOCKS, 256, 0, stream>>>(srcArr, dstArr, tmp, bsums, binned);
  k_bbase<<<1, 128, 0, stream>>>(tmp, bsums, bucket_base);
  k_scatter3<<<NBK, 256, 0, stream>>>(bucket_base, binned, row_ptr, csr_src);
  k_gemm0m<<<(N_NODES + 63) / 64, 256, 0, stream>>>(data, W0t, att_src0, att_dst0, h0, a_s0,
                                                    a_d0);
  k_wts0<<<(N_NODES + 3) / 4, 256, 0, stream>>>(row_ptr, csr_src, a_s0, a_d0, wts0, selfw0);
  k_acc0<<<(N_NODES + 3) / 4, 256, 0, stream>>>(row_ptr, csr_src, h0, wts0, selfw0, bias0, out0);
  k_bnstats<<<1024, 256, 0, stream>>>(out0, bn_sum, bn_sumsq);
  k_bnfinal<<<1, 128, 0, stream>>>(bn_sum, bn_sumsq, gamma0, beta0, bn_scale, bn_shift);
  k_gemm1m<<<(N_NODES + 63) / 64, 256, 0, stream>>>(out0, bn_scale, bn_shift, W1t, att_src1,
                                                    att_dst1, h1, a_s1, a_d1);
  k_wts1<<<(N_NODES + 3) / 4, 256, 0, stream>>>(row_ptr, csr_src, a_s1, a_d1, wts1, selfw1);
  k_acc1<<<(N_NODES + 3) / 4, 256, 0, stream>>>(row_ptr, csr_src, h1, wts1, selfw1, bias1, out);
}

// Round 11
// 304.599 us; speedup vs baseline: 1.1339x; 1.0845x over previous
//
#include <hip/hip_runtime.h>
#include <hip/hip_fp16.h>
#include <math.h>

#define N_NODES 50000
#define E_EDGES 800000
#define NEG_SLOPE 0.2f
#define BN_EPS 1e-5f

#define BK_SHIFT 9                       // 512-node buckets
#define NBK 98                           // ceil(50000/512)
#define L1_BLOCKS 256
#define L1_CHUNK (E_EDGES / L1_BLOCKS)   // 3125 exactly
#define CNT_N (NBK * L1_BLOCKS)          // 25088
#define SCG_BLOCKS ((CNT_N + 1023) / 1024)  // 25
#define STAGE_MAX 9216                   // per-bucket staging

typedef __attribute__((ext_vector_type(8))) _Float16 half8;
typedef __attribute__((ext_vector_type(4))) float f32x4;

__device__ __forceinline__ float lrelu(float v) { return v > 0.f ? v : NEG_SLOPE * v; }

// ---------------- init (BN accumulators only) ----------------
__global__ void k_zero(float* __restrict__ bn_sum, float* __restrict__ bn_sumsq) {
  int t = threadIdx.x;
  if (t < 128) { bn_sum[t] = 0.f; bn_sumsq[t] = 0.f; }
}

// ---------------- fp16 weight transpose-converts ----------------
__global__ void k_cvtW(const float* __restrict__ W0, const float* __restrict__ W1,
                       _Float16* __restrict__ W0t, _Float16* __restrict__ W1t) {
  int t = threadIdx.x;
  for (int idx = t; idx < 128 * 128; idx += 256) {
    int k = idx >> 7, c = idx & 127;
    W0t[c * 128 + k] = (_Float16)W0[idx];
  }
  for (int idx = t; idx < 128 * 64; idx += 256) {
    int k = idx >> 6, c = idx & 63;
    W1t[c * 128 + k] = (_Float16)W1[idx];
  }
}

// ---- L1: per-block bucket histogram ----
__global__ __launch_bounds__(256) void k_l1hist(const int* __restrict__ dst,
                                                int* __restrict__ cnt) {
  __shared__ int lcnt[NBK];
  int t = threadIdx.x;
  if (t < NBK) lcnt[t] = 0;
  __syncthreads();
  int beg = blockIdx.x * L1_CHUNK, end = beg + L1_CHUNK;
  for (int e = beg + t; e < end; e += 256)
    atomicAdd(&lcnt[((unsigned int)dst[e]) >> BK_SHIFT], 1);
  __syncthreads();
  for (int b = t; b < NBK; b += 256) cnt[b * L1_BLOCKS + blockIdx.x] = lcnt[b];
}

// ---- hierarchical exclusive scan over CNT_N ----
__global__ __launch_bounds__(256) void k_scan1g(const int* __restrict__ cnt,
                                                int* __restrict__ tmp,
                                                int* __restrict__ bsums) {
  __shared__ int ts[256];
  int t = threadIdx.x;
  int base = blockIdx.x * 1024 + t * 4;
  int c0 = (base + 0 < CNT_N) ? cnt[base + 0] : 0;
  int c1 = (base + 1 < CNT_N) ? cnt[base + 1] : 0;
  int c2 = (base + 2 < CNT_N) ? cnt[base + 2] : 0;
  int c3 = (base + 3 < CNT_N) ? cnt[base + 3] : 0;
  int s = c0 + c1 + c2 + c3;
  ts[t] = s;
  __syncthreads();
  for (int off = 1; off < 256; off <<= 1) {
    int v = (t >= off) ? ts[t - off] : 0;
    __syncthreads();
    ts[t] += v;
    __syncthreads();
  }
  int excl = ts[t] - s;
  if (t == 255) bsums[blockIdx.x] = ts[255];
  if (base + 0 < CNT_N) tmp[base + 0] = excl;
  if (base + 1 < CNT_N) tmp[base + 1] = excl + c0;
  if (base + 2 < CNT_N) tmp[base + 2] = excl + c0 + c1;
  if (base + 3 < CNT_N) tmp[base + 3] = excl + c0 + c1 + c2;
}

__global__ void k_scan2g(int* __restrict__ bsums) {
  int t = threadIdx.x;
  int orig = (t < SCG_BLOCKS) ? bsums[t] : 0;
  int v = orig;
#pragma unroll
  for (int off = 1; off < 64; off <<= 1) {
    int u = __shfl_up(v, off);
    if (t >= off) v += u;
  }
  if (t < SCG_BLOCKS) bsums[t] = v - orig;
}

// ---- L1 scatter: deterministic bases per (bucket,block) ----
__global__ __launch_bounds__(256) void k_l1scatter(const int* __restrict__ src,
                                                   const int* __restrict__ dst,
                                                   const int* __restrict__ tmp,
                                                   const int* __restrict__ bsums,
                                                   unsigned int* __restrict__ binned) {
  __shared__ int cur[NBK];
  int t = threadIdx.x;
  for (int b = t; b < NBK; b += 256) {
    int idx = b * L1_BLOCKS + blockIdx.x;
    cur[b] = tmp[idx] + bsums[idx >> 10];
  }
  __syncthreads();
  int beg = blockIdx.x * L1_CHUNK, end = beg + L1_CHUNK;
  for (int e = beg + t; e < end; e += 256) {
    unsigned int d = (unsigned int)dst[e];
    int b = d >> BK_SHIFT;
    int p = atomicAdd(&cur[b], 1);
    binned[p] = ((unsigned int)src[e] << 16) | d;
  }
}

__global__ void k_bbase(const int* __restrict__ tmp, const int* __restrict__ bsums,
                        int* __restrict__ bucket_base) {
  int b = threadIdx.x;
  if (b < NBK) {
    int idx = b * L1_BLOCKS;
    bucket_base[b] = tmp[idx] + bsums[idx >> 10];
  }
  if (b == NBK) bucket_base[NBK] = E_EDGES;
}

// ---- L2: per-bucket LDS counting sort ----
__global__ __launch_bounds__(256) void k_scatter3(const int* __restrict__ bucket_base,
                                                  const unsigned int* __restrict__ binned,
                                                  int* __restrict__ row_ptr,
                                                  int* __restrict__ csr_src) {
  __shared__ int cnt[512];
  __shared__ int staging[STAGE_MAX];
  __shared__ int ts[256];
  int t = threadIdx.x;
  int b = blockIdx.x;
  int lo = b << BK_SHIFT;
  int hi = lo + 512; if (hi > N_NODES) hi = N_NODES;
  int nloc = hi - lo;
  int base = bucket_base[b];
  int end = bucket_base[b + 1];
  cnt[t] = 0; cnt[t + 256] = 0;
  __syncthreads();
  for (int i = base + t; i < end; i += 256)
    atomicAdd(&cnt[(binned[i] & 0xFFFFu) - lo], 1);
  __syncthreads();
  int c0 = cnt[2 * t], c1 = cnt[2 * t + 1];
  int pair = c0 + c1;
  ts[t] = pair;
  __syncthreads();
  for (int off = 1; off < 256; off <<= 1) {
    int v = (t >= off) ? ts[t - off] : 0;
    __syncthreads();
    ts[t] += v;
    __syncthreads();
  }
  int exclp = ts[t] - pair;
  cnt[2 * t] = exclp;
  cnt[2 * t + 1] = exclp + c0;
  if (2 * t < nloc) row_ptr[lo + 2 * t] = base + exclp;
  if (2 * t + 1 < nloc) row_ptr[lo + 2 * t + 1] = base + exclp + c0;
  if (b == NBK - 1 && t == 0) row_ptr[N_NODES] = E_EDGES;
  __syncthreads();
  for (int i = base + t; i < end; i += 256) {
    unsigned int v = binned[i];
    int d = (int)(v & 0xFFFFu) - lo;
    int p = atomicAdd(&cnt[d], 1);
    int s = (int)(v >> 16);
    if (p < STAGE_MAX) staging[p] = s;
    else csr_src[base + p] = s;
  }
  __syncthreads();
  int tot = end - base;
  int lim = tot < STAGE_MAX ? tot : STAGE_MAX;
  for (int k = t; k < lim; k += 256) csr_src[base + k] = staging[k];
}

// ------- layer 0 GEMM via f16 MFMA, fp32 A-load fused convert -------
__global__ __launch_bounds__(256) void k_gemm0m(
    const float* __restrict__ x, const _Float16* __restrict__ Wt,
    const float* __restrict__ att_s, const float* __restrict__ att_d,
    _Float16* __restrict__ h, float* __restrict__ a_src, float* __restrict__ a_dst) {
  int lane = threadIdx.x & 63;
  int wv = threadIdx.x >> 6;
  int row0 = blockIdx.x * 64 + wv * 16;
  int m = lane & 15, kg = lane >> 4;
  int arow = row0 + m;
  int arowc = arow < N_NODES ? arow : N_NODES - 1;
  f32x4 acc[8];
#pragma unroll
  for (int ct = 0; ct < 8; ct++) acc[ct] = (f32x4){0.f, 0.f, 0.f, 0.f};
#pragma unroll
  for (int kc = 0; kc < 4; kc++) {
    const float* xp = &x[(size_t)arowc * 128 + kc * 32 + kg * 8];
    float4 xa = *(const float4*)xp;
    float4 xb = *(const float4*)(xp + 4);
    half8 af = {(_Float16)xa.x, (_Float16)xa.y, (_Float16)xa.z, (_Float16)xa.w,
                (_Float16)xb.x, (_Float16)xb.y, (_Float16)xb.z, (_Float16)xb.w};
#pragma unroll
    for (int ct = 0; ct < 8; ct++) {
      half8 bf = *(const half8*)&Wt[(ct * 16 + m) * 128 + kc * 32 + kg * 8];
      acc[ct] = __builtin_amdgcn_mfma_f32_16x16x32_f16(af, bf, acc[ct], 0, 0, 0);
    }
  }
  float as[8], ad[8];
#pragma unroll
  for (int ct = 0; ct < 8; ct++) { as[ct] = att_s[ct * 16 + m]; ad[ct] = att_d[ct * 16 + m]; }
#pragma unroll
  for (int r = 0; r < 4; r++) {
    int row = row0 + kg * 4 + r;
    bool ok = row < N_NODES;
    float ps0 = 0.f, pd0 = 0.f, ps1 = 0.f, pd1 = 0.f;
#pragma unroll
    for (int ct = 0; ct < 4; ct++) { ps0 += acc[ct][r] * as[ct]; pd0 += acc[ct][r] * ad[ct]; }
#pragma unroll
    for (int ct = 4; ct < 8; ct++) { ps1 += acc[ct][r] * as[ct]; pd1 += acc[ct][r] * ad[ct]; }
#pragma unroll
    for (int msk = 1; msk <= 8; msk <<= 1) {
      ps0 += __shfl_xor(ps0, msk); pd0 += __shfl_xor(pd0, msk);
      ps1 += __shfl_xor(ps1, msk); pd1 += __shfl_xor(pd1, msk);
    }
    if (ok) {
#pragma unroll
      for (int ct = 0; ct < 8; ct++)
        h[(size_t)row * 128 + ct * 16 + m] = (_Float16)acc[ct][r];
      if (m == 0) {
        a_src[row * 2 + 0] = ps0; a_dst[row * 2 + 0] = pd0;
        a_src[row * 2 + 1] = ps1; a_dst[row * 2 + 1] = pd1;
      }
    }
  }
}

// ------- layer 1 GEMM via f16 MFMA, BN+ELU fused into A-load -------
__global__ __launch_bounds__(256) void k_gemm1m(
    const float* __restrict__ y, const float* __restrict__ scale,
    const float* __restrict__ shift, const _Float16* __restrict__ Wt,
    const float* __restrict__ att_s, const float* __restrict__ att_d,
    _Float16* __restrict__ h, float* __restrict__ a_src, float* __restrict__ a_dst) {
  int lane = threadIdx.x & 63;
  int wv = threadIdx.x >> 6;
  int row0 = blockIdx.x * 64 + wv * 16;
  int m = lane & 15, kg = lane >> 4;
  int arow = row0 + m;
  int arowc = arow < N_NODES ? arow : N_NODES - 1;
  f32x4 acc[4];
#pragma unroll
  for (int ct = 0; ct < 4; ct++) acc[ct] = (f32x4){0.f, 0.f, 0.f, 0.f};
#pragma unroll
  for (int kc = 0; kc < 4; kc++) {
    int kb = kc * 32 + kg * 8;
    const float* yp = &y[(size_t)arowc * 128 + kb];
    float4 ya = *(const float4*)yp;
    float4 yb = *(const float4*)(yp + 4);
    float4 sa = *(const float4*)&scale[kb], sb = *(const float4*)&scale[kb + 4];
    float4 fa = *(const float4*)&shift[kb], fb = *(const float4*)&shift[kb + 4];
    float v[8];
    v[0] = ya.x * sa.x + fa.x; v[1] = ya.y * sa.y + fa.y;
    v[2] = ya.z * sa.z + fa.z; v[3] = ya.w * sa.w + fa.w;
    v[4] = yb.x * sb.x + fb.x; v[5] = yb.y * sb.y + fb.y;
    v[6] = yb.z * sb.z + fb.z; v[7] = yb.w * sb.w + fb.w;
    half8 af;
#pragma unroll
    for (int j = 0; j < 8; j++) {
      float e = v[j] > 0.f ? v[j] : __expf(v[j]) - 1.f;
      af[j] = (_Float16)e;
    }
#pragma unroll
    for (int ct = 0; ct < 4; ct++) {
      half8 bf = *(const half8*)&Wt[(ct * 16 + m) * 128 + kb];
      acc[ct] = __builtin_amdgcn_mfma_f32_16x16x32_f16(af, bf, acc[ct], 0, 0, 0);
    }
  }
  float as[4], ad[4];
#pragma unroll
  for (int ct = 0; ct < 4; ct++) { as[ct] = att_s[ct * 16 + m]; ad[ct] = att_d[ct * 16 + m]; }
#pragma unroll
  for (int r = 0; r < 4; r++) {
    int row = row0 + kg * 4 + r;
    bool ok = row < N_NODES;
    float ps = 0.f, pd = 0.f;
#pragma unroll
    for (int ct = 0; ct < 4; ct++) { ps += acc[ct][r] * as[ct]; pd += acc[ct][r] * ad[ct]; }
#pragma unroll
    for (int msk = 1; msk <= 8; msk <<= 1) {
      ps += __shfl_xor(ps, msk); pd += __shfl_xor(pd, msk);
    }
    if (ok) {
#pragma unroll
      for (int ct = 0; ct < 4; ct++)
        h[(size_t)row * 64 + ct * 16 + m] = (_Float16)acc[ct][r];
      if (m == 0) { a_src[row] = ps; a_dst[row] = pd; }
    }
  }
}

// ------- layer 0 FUSED aggregation: phase A edge-parallel softmax stats,
//         phase B 16ch x 4way wide gathers with inline weights -------
__global__ __launch_bounds__(256) void k_fagg0(
    const int* __restrict__ row_ptr, const int* __restrict__ csr_src,
    const _Float16* __restrict__ h, const float* __restrict__ a_src,
    const float* __restrict__ a_dst, const float* __restrict__ bias,
    float* __restrict__ out) {
  int node = (blockIdx.x * blockDim.x + threadIdx.x) >> 6;
  if (node >= N_NODES) return;
  int l = threadIdx.x & 63;
  float ad0 = a_dst[node * 2], ad1 = a_dst[node * 2 + 1];
  float es0 = lrelu(a_src[node * 2] + ad0);
  float es1 = lrelu(a_src[node * 2 + 1] + ad1);
  int beg = row_ptr[node], end = row_ptr[node + 1];
  // phase A: per-lane online (m,s), then 6-step merge
  const float NEGBIG = -3.0e38f;
  float m0 = NEGBIG, s0 = 0.f, m1 = NEGBIG, s1 = 0.f;
  for (int j = beg + l; j < end; j += 64) {
    int s = csr_src[j];
    float2 asv = *(const float2*)&a_src[s * 2];
    float e0 = lrelu(asv.x + ad0), e1 = lrelu(asv.y + ad1);
    float nm0 = fmaxf(m0, e0);
    s0 = s0 * __expf(m0 - nm0) + __expf(e0 - nm0); m0 = nm0;
    float nm1 = fmaxf(m1, e1);
    s1 = s1 * __expf(m1 - nm1) + __expf(e1 - nm1); m1 = nm1;
  }
#pragma unroll
  for (int msk = 1; msk < 64; msk <<= 1) {
    float om0 = __shfl_xor(m0, msk), os0 = __shfl_xor(s0, msk);
    float nm0 = fmaxf(m0, om0);
    s0 = s0 * __expf(m0 - nm0) + os0 * __expf(om0 - nm0); m0 = nm0;
    float om1 = __shfl_xor(m1, msk), os1 = __shfl_xor(s1, msk);
    float nm1 = fmaxf(m1, om1);
    s1 = s1 * __expf(m1 - nm1) + os1 * __expf(om1 - nm1); m1 = nm1;
  }
  float fm0 = fmaxf(m0, es0), fm1 = fmaxf(m1, es1);
  float inv0 = 1.f / (s0 * __expf(m0 - fm0) + __expf(es0 - fm0));
  float inv1 = 1.f / (s1 * __expf(m1 - fm1) + __expf(es1 - fm1));
  // phase B: channel x way accumulate
  int cl = l & 15, ew = l >> 4;
  int cbase = cl * 8;
  int head = cl >> 3;
  float adh = head ? ad1 : ad0;
  float fmh = head ? fm1 : fm0;
  float invh = head ? inv1 : inv0;
  float acc[8];
#pragma unroll
  for (int k = 0; k < 8; k++) acc[k] = 0.f;
  if (ew == 0) {
    float wself = head ? __expf(es1 - fm1) * inv1 : __expf(es0 - fm0) * inv0;
    half8 hv = *(const half8*)&h[(size_t)node * 128 + cbase];
#pragma unroll
    for (int k = 0; k < 8; k++) acc[k] += wself * (float)hv[k];
  }
  int deg = end - beg;
  int nt = (deg + 3) >> 2;
  int t = 0;
  for (; t + 1 < nt; t += 2) {  // 2 edges in flight per way
    int j0 = beg + t * 4 + ew, j1 = j0 + 4;
    bool v0 = j0 < end, v1 = j1 < end;
    int sA = v0 ? csr_src[j0] : node;
    int sB = v1 ? csr_src[j1] : node;
    float eA = lrelu(a_src[sA * 2 + head] + adh);
    float eB = lrelu(a_src[sB * 2 + head] + adh);
    float wA = v0 ? __expf(eA - fmh) * invh : 0.f;
    float wB = v1 ? __expf(eB - fmh) * invh : 0.f;
    half8 hA = *(const half8*)&h[(size_t)sA * 128 + cbase];
    half8 hB = *(const half8*)&h[(size_t)sB * 128 + cbase];
#pragma unroll
    for (int k = 0; k < 8; k++) acc[k] += wA * (float)hA[k] + wB * (float)hB[k];
  }
  if (t < nt) {
    int j0 = beg + t * 4 + ew;
    bool v0 = j0 < end;
    int sA = v0 ? csr_src[j0] : node;
    float eA = lrelu(a_src[sA * 2 + head] + adh);
    float wA = v0 ? __expf(eA - fmh) * invh : 0.f;
    half8 hA = *(const half8*)&h[(size_t)sA * 128 + cbase];
#pragma unroll
    for (int k = 0; k < 8; k++) acc[k] += wA * (float)hA[k];
  }
#pragma unroll
  for (int k = 0; k < 8; k++) {
    acc[k] += __shfl_xor(acc[k], 16);
    acc[k] += __shfl_xor(acc[k], 32);
  }
  if (ew == 0) {
    float4 b0 = *(const float4*)&bias[cbase];
    float4 b1 = *(const float4*)&bias[cbase + 4];
    float4 o0 = make_float4(acc[0] + b0.x, acc[1] + b0.y, acc[2] + b0.z, acc[3] + b0.w);
    float4 o1 = make_float4(acc[4] + b1.x, acc[5] + b1.y, acc[6] + b1.z, acc[7] + b1.w);
    *(float4*)&out[(size_t)node * 128 + cbase] = o0;
    *(float4*)&out[(size_t)node * 128 + cbase + 4] = o1;
  }
}

// ---------------- BatchNorm stats ----------------
__global__ __launch_bounds__(256) void k_bnstats(const float* __restrict__ x,
                                                 float* __restrict__ bn_sum,
                                                 float* __restrict__ bn_sumsq) {
  int f = threadIdx.x & 127;
  int half = threadIdx.x >> 7;
  float s = 0.f, s2 = 0.f;
  for (int r = blockIdx.x * 2 + half; r < N_NODES; r += gridDim.x * 2) {
    float v = x[(size_t)r * 128 + f];
    s += v;
    s2 += v * v;
  }
  __shared__ float ls[256], ls2[256];
  ls[threadIdx.x] = s;
  ls2[threadIdx.x] = s2;
  __syncthreads();
  if (half == 0) {
    atomicAdd(&bn_sum[f], s + ls[f + 128]);
    atomicAdd(&bn_sumsq[f], s2 + ls2[f + 128]);
  }
}

__global__ void k_bnfinal(const float* __restrict__ sum, const float* __restrict__ sumsq,
                          const float* __restrict__ gamma, const float* __restrict__ beta,
                          float* __restrict__ scale, float* __restrict__ shift) {
  int f = threadIdx.x;
  float mu = sum[f] / (float)N_NODES;
  float var = sumsq[f] / (float)N_NODES - mu * mu;
  float sc = gamma[f] * rsqrtf(var + BN_EPS);
  scale[f] = sc;
  shift[f] = beta[f] - mu * sc;
}

// ------- layer 1 FUSED aggregation: 8ch x 8way -------
__global__ __launch_bounds__(256) void k_fagg1(
    const int* __restrict__ row_ptr, const int* __restrict__ csr_src,
    const _Float16* __restrict__ h, const float* __restrict__ a_src,
    const float* __restrict__ a_dst, const float* __restrict__ bias,
    float* __restrict__ out) {
  int node = (blockIdx.x * blockDim.x + threadIdx.x) >> 6;
  if (node >= N_NODES) return;
  int l = threadIdx.x & 63;
  float ad = a_dst[node];
  float es = lrelu(a_src[node] + ad);
  int beg = row_ptr[node], end = row_ptr[node + 1];
  const float NEGBIG = -3.0e38f;
  float m = NEGBIG, s = 0.f;
  for (int j = beg + l; j < end; j += 64) {
    int sn = csr_src[j];
    float e = lrelu(a_src[sn] + ad);
    float nm = fmaxf(m, e);
    s = s * __expf(m - nm) + __expf(e - nm); m = nm;
  }
#pragma unroll
  for (int msk = 1; msk < 64; msk <<= 1) {
    float om = __shfl_xor(m, msk), os = __shfl_xor(s, msk);
    float nm = fmaxf(m, om);
    s = s * __expf(m - nm) + os * __expf(om - nm); m = nm;
  }
  float fm = fmaxf(m, es);
  float inv = 1.f / (s * __expf(m - fm) + __expf(es - fm));
  int cl = l & 7, ew = l >> 3;
  int cbase = cl * 8;
  float acc[8];
#pragma unroll
  for (int k = 0; k < 8; k++) acc[k] = 0.f;
  if (ew == 0) {
    float wself = __expf(es - fm) * inv;
    half8 hv = *(const half8*)&h[(size_t)node * 64 + cbase];
#pragma unroll
    for (int k = 0; k < 8; k++) acc[k] += wself * (float)hv[k];
  }
  int deg = end - beg;
  int nt = (deg + 7) >> 3;
  int t = 0;
  for (; t + 1 < nt; t += 2) {
    int j0 = beg + t * 8 + ew, j1 = j0 + 8;
    bool v0 = j0 < end, v1 = j1 < end;
    int sA = v0 ? csr_src[j0] : node;
    int sB = v1 ? csr_src[j1] : node;
    float eA = lrelu(a_src[sA] + ad);
    float eB = lrelu(a_src[sB] + ad);
    float wA = v0 ? __expf(eA - fm) * inv : 0.f;
    float wB = v1 ? __expf(eB - fm) * inv : 0.f;
    half8 hA = *(const half8*)&h[(size_t)sA * 64 + cbase];
    half8 hB = *(const half8*)&h[(size_t)sB * 64 + cbase];
#pragma unroll
    for (int k = 0; k < 8; k++) acc[k] += wA * (float)hA[k] + wB * (float)hB[k];
  }
  if (t < nt) {
    int j0 = beg + t * 8 + ew;
    bool v0 = j0 < end;
    int sA = v0 ? csr_src[j0] : node;
    float eA = lrelu(a_src[sA] + ad);
    float wA = v0 ? __expf(eA - fm) * inv : 0.f;
    half8 hA = *(const half8*)&h[(size_t)sA * 64 + cbase];
#pragma unroll
    for (int k = 0; k < 8; k++) acc[k] += wA * (float)hA[k];
  }
#pragma unroll
  for (int k = 0; k < 8; k++) {
    acc[k] += __shfl_xor(acc[k], 8);
    acc[k] += __shfl_xor(acc[k], 16);
    acc[k] += __shfl_xor(acc[k], 32);
  }
  if (ew == 0) {
    float4 b0 = *(const float4*)&bias[cbase];
    float4 b1 = *(const float4*)&bias[cbase + 4];
    float4 o0 = make_float4(acc[0] + b0.x, acc[1] + b0.y, acc[2] + b0.z, acc[3] + b0.w);
    float4 o1 = make_float4(acc[4] + b1.x, acc[5] + b1.y, acc[6] + b1.z, acc[7] + b1.w);
    *(float4*)&out[(size_t)node * 64 + cbase] = o0;
    *(float4*)&out[(size_t)node * 64 + cbase + 4] = o1;
  }
}

// ---------------- launch ----------------
extern "C" void kernel_launch(void* const* d_in, const int* in_sizes, int n_in,
                              void* d_out, int out_size, void* d_ws, size_t ws_size,
                              hipStream_t stream) {
  const float* data = (const float*)d_in[0];
  const int* ei = (const int*)d_in[1];
  const float* W0 = (const float*)d_in[2];
  const float* att_src0 = (const float*)d_in[3];
  const float* att_dst0 = (const float*)d_in[4];
  const float* bias0 = (const float*)d_in[5];
  const float* gamma0 = (const float*)d_in[6];
  const float* beta0 = (const float*)d_in[7];
  const float* W1 = (const float*)d_in[8];
  const float* att_src1 = (const float*)d_in[9];
  const float* att_dst1 = (const float*)d_in[10];
  const float* bias1 = (const float*)d_in[11];
  float* out = (float*)d_out;

  char* ws = (char*)d_ws;
  size_t off = 0;
  auto alloc = [&](size_t bytes) -> void* {
    void* p = ws + off;
    off = (off + bytes + 255) & ~(size_t)255;
    return p;
  };
  int* cnt = (int*)alloc((size_t)CNT_N * 4);
  int* tmp = (int*)alloc((size_t)CNT_N * 4);
  int* bsums = (int*)alloc(32 * 4);
  int* bucket_base = (int*)alloc((NBK + 1) * 4);
  int* row_ptr = (int*)alloc((N_NODES + 1) * 4);
  unsigned int* binned = (unsigned int*)alloc((size_t)E_EDGES * 4);
  int* csr_src = (int*)alloc((size_t)E_EDGES * 4);
  _Float16* W0t = (_Float16*)alloc(128 * 128 * 2);
  _Float16* W1t = (_Float16*)alloc(64 * 128 * 2);
  _Float16* h0 = (_Float16*)alloc((size_t)N_NODES * 128 * 2);
  float* a_s0 = (float*)alloc((size_t)N_NODES * 2 * 4);
  float* a_d0 = (float*)alloc((size_t)N_NODES * 2 * 4);
  float* out0 = (float*)alloc((size_t)N_NODES * 128 * 4);
  float* bn_sum = (float*)alloc(128 * 4);
  float* bn_sumsq = (float*)alloc(128 * 4);
  float* bn_scale = (float*)alloc(128 * 4);
  float* bn_shift = (float*)alloc(128 * 4);
  _Float16* h1 = h0;  // alias: h0 dead after fagg0
  float* a_s1 = a_s0;
  float* a_d1 = a_d0;

  const int* srcArr = ei;
  const int* dstArr = ei + E_EDGES;

  k_zero<<<1, 128, 0, stream>>>(bn_sum, bn_sumsq);
  k_cvtW<<<1, 256, 0, stream>>>(W0, W1, W0t, W1t);
  k_l1hist<<<L1_BLOCKS, 256, 0, stream>>>(dstArr, cnt);
  k_scan1g<<<SCG_BLOCKS, 256, 0, stream>>>(cnt, tmp, bsums);
  k_scan2g<<<1, 64, 0, stream>>>(bsums);
  k_l1scatter<<<L1_BLOCKS, 256, 0, stream>>>(srcArr, dstArr, tmp, bsums, binned);
  k_bbase<<<1, 128, 0, stream>>>(tmp, bsums, bucket_base);
  k_scatter3<<<NBK, 256, 0, stream>>>(bucket_base, binned, row_ptr, csr_src);
  k_gemm0m<<<(N_NODES + 63) / 64, 256, 0, stream>>>(data, W0t, att_src0, att_dst0, h0, a_s0,
                                                    a_d0);
  k_fagg0<<<(N_NODES + 3) / 4, 256, 0, stream>>>(row_ptr, csr_src, h0, a_s0, a_d0, bias0, out0);
  k_bnstats<<<1024, 256, 0, stream>>>(out0, bn_sum, bn_sumsq);
  k_bnfinal<<<1, 128, 0, stream>>>(bn_sum, bn_sumsq, gamma0, beta0, bn_scale, bn_shift);
  k_gemm1m<<<(N_NODES + 63) / 64, 256, 0, stream>>>(out0, bn_scale, bn_shift, W1t, att_src1,
                                                    att_dst1, h1, a_s1, a_d1);
  k_fagg1<<<(N_NODES + 3) / 4, 256, 0, stream>>>(row_ptr, csr_src, h1, a_s1, a_d1, bias1, out);
}